// Round 1
// baseline (23874.551 us; speedup 1.0000x reference)
//
#include <hip/hip_runtime.h>
#include <hip/hip_bf16.h>
#include <math.h>

#define EPS_REEIG 0.01f

// ---------------------------------------------------------------------------
// BiMap: Y[b] = W^T X[b] W.  One block per batch element.
// Stages W and T = X*W in LDS.
// ---------------------------------------------------------------------------
template<int NIN, int NOUT, int BT>
__global__ void bimap_kernel(const float* __restrict__ X,
                             const float* __restrict__ W,
                             float* __restrict__ Y) {
    __shared__ float Ws[NIN * NOUT];
    __shared__ float T[NIN * NOUT];
    const int b = blockIdx.x;
    const float* Xb = X + (size_t)b * NIN * NIN;

    for (int e = threadIdx.x; e < NIN * NOUT; e += BT) Ws[e] = W[e];
    __syncthreads();

    // T = X * W   [NIN x NOUT]
    for (int e = threadIdx.x; e < NIN * NOUT; e += BT) {
        const int i = e / NOUT;
        const int j = e % NOUT;
        float acc = 0.f;
        const float* xrow = Xb + (size_t)i * NIN;
#pragma unroll 8
        for (int k = 0; k < NIN; ++k) acc += xrow[k] * Ws[k * NOUT + j];
        T[e] = acc;
    }
    __syncthreads();

    // Y = W^T * T  [NOUT x NOUT]
    for (int e = threadIdx.x; e < NOUT * NOUT; e += BT) {
        const int p = e / NOUT;
        const int q = e % NOUT;
        float acc = 0.f;
#pragma unroll 8
        for (int k = 0; k < NIN; ++k) acc += Ws[k * NOUT + p] * T[k * NOUT + q];
        Y[(size_t)b * NOUT * NOUT + e] = acc;
    }
}

// ---------------------------------------------------------------------------
// Batched symmetric eigendecomposition via parallel cyclic Jacobi
// (round-robin tournament ordering). One block per matrix.
// If FINAL==false: writes ReEig reconstruction V*max(w,eps)*V^T to Out[b*N*N].
// If FINAL==true : computes L = V*log(max(w,eps))*V^T, then vech(L) @ fc_w^T
//                  + fc_b, writing 7 floats to Out[b*7].
// ---------------------------------------------------------------------------
template<int N, int SWEEPS, int BT, bool FINAL>
__global__ void eig_kernel(const float* In, float* Out,
                           const float* __restrict__ fc_w,
                           const float* __restrict__ fc_b) {
    constexpr int P = N + 1;   // padded pitch (bank-conflict avoidance)
    constexpr int H = N / 2;   // independent rotations per round
    __shared__ float A[N * P];
    __shared__ float V[N * P];
    __shared__ float cs[H], sn[H];
    __shared__ int   pr[H], qr[H];
    __shared__ float fw[N];

    const int b = blockIdx.x;
    const float* inb = In + (size_t)b * N * N;

    for (int e = threadIdx.x; e < N * N; e += BT) {
        const int i = e / N;
        const int j = e % N;
        A[i * P + j] = inb[e];
        V[i * P + j] = (i == j) ? 1.f : 0.f;
    }
    __syncthreads();

    for (int sw = 0; sw < SWEEPS; ++sw) {
        for (int r = 0; r < N - 1; ++r) {
            // ---- compute the H independent rotations of this round ----
            if (threadIdx.x < H) {
                const int k = threadIdx.x;
                const int m = N - 1;
                int p, q;
                if (k == 0) {
                    p = r % m; q = m;
                } else {
                    const int a0 = (r + k) % m;
                    const int a1 = (r + m - k) % m;
                    p = min(a0, a1); q = max(a0, a1);
                }
                const float apq = A[p * P + q];
                float c = 1.f, s = 0.f;
                if (fabsf(apq) > 1e-36f) {
                    const float app = A[p * P + p];
                    const float aqq = A[q * P + q];
                    const float tau = (aqq - app) / (2.f * apq);
                    const float t = copysignf(1.f, tau) /
                                    (fabsf(tau) + sqrtf(1.f + tau * tau));
                    c = rsqrtf(1.f + t * t);
                    s = t * c;
                }
                cs[k] = c; sn[k] = s; pr[k] = p; qr[k] = q;
            }
            __syncthreads();

            // ---- row update: A = J^T A ----
            for (int t = threadIdx.x; t < H * N; t += BT) {
                const int k = t / N;
                const int col = t % N;
                const int p = pr[k], q = qr[k];
                const float c = cs[k], s = sn[k];
                const float ap = A[p * P + col];
                const float aq = A[q * P + col];
                A[p * P + col] = c * ap - s * aq;
                A[q * P + col] = s * ap + c * aq;
            }
            __syncthreads();

            // ---- column update: A = A J, and V = V J ----
            for (int t = threadIdx.x; t < 2 * H * N; t += BT) {
                const int half = t / (H * N);
                const int tt = t % (H * N);
                const int k = tt / N;
                const int row = tt % N;
                const int p = pr[k], q = qr[k];
                const float c = cs[k], s = sn[k];
                float* M = half ? V : A;
                const float mp = M[row * P + p];
                const float mq = M[row * P + q];
                M[row * P + p] = c * mp - s * mq;
                M[row * P + q] = s * mp + c * mq;
            }
            __syncthreads();
        }
    }

    // ---- eigenvalues on the diagonal; apply spectral function ----
    if (threadIdx.x < N) {
        const float w = A[threadIdx.x * P + threadIdx.x];
        const float wc = fmaxf(w, EPS_REEIG);
        fw[threadIdx.x] = FINAL ? logf(wc) : wc;
    }
    __syncthreads();

    // ---- reconstruct  R[i][j] = sum_k V[i][k] * fw[k] * V[j][k] ----
    for (int e = threadIdx.x; e < N * N; e += BT) {
        const int i = e / N;
        const int j = e % N;
        float acc = 0.f;
#pragma unroll 8
        for (int k = 0; k < N; ++k)
            acc += V[i * P + k] * fw[k] * V[j * P + k];
        if (FINAL) {
            A[i * P + j] = acc;          // keep in LDS for vech+FC
        } else {
            Out[(size_t)b * N * N + e] = acc;
        }
    }

    if (FINAL) {
        __syncthreads();
        // vech (upper triangle, row-major) -> FC [7 x 136]
        if (threadIdx.x < 7) {
            const int c = threadIdx.x;
            float acc = fc_b[c];
            int idx = 0;
            for (int i = 0; i < N; ++i)
                for (int j = i; j < N; ++j)
                    acc += fc_w[c * 136 + idx++] * A[i * P + j];
            Out[(size_t)b * 7 + c] = acc;
        }
    }
}

// ---------------------------------------------------------------------------
extern "C" void kernel_launch(void* const* d_in, const int* in_sizes, int n_in,
                              void* d_out, int out_size, void* d_ws, size_t ws_size,
                              hipStream_t stream) {
    const float* x    = (const float*)d_in[0];   // [B,128,128]
    const float* W1   = (const float*)d_in[1];   // [128,64]
    const float* W2   = (const float*)d_in[2];   // [64,32]
    const float* W3   = (const float*)d_in[3];   // [32,16]
    const float* fc_w = (const float*)d_in[4];   // [7,136]
    const float* fc_b = (const float*)d_in[5];   // [7]
    float* out = (float*)d_out;                  // [B,7]

    const int B = in_sizes[0] / (128 * 128);

    // workspace layout
    float* y1 = (float*)d_ws;                          // [B,64,64] 134 MB
    float* y2 = y1 + (size_t)B * 64 * 64;              // [B,32,32]  33 MB
    float* y3 = y2 + (size_t)B * 32 * 32;              // [B,16,16] 8.4 MB

    bimap_kernel<128, 64, 256><<<B, 256, 0, stream>>>(x, W1, y1);
    eig_kernel<64, 10, 256, false><<<B, 256, 0, stream>>>(y1, y1, nullptr, nullptr);
    bimap_kernel<64, 32, 256><<<B, 256, 0, stream>>>(y1, W2, y2);
    eig_kernel<32, 9, 256, false><<<B, 256, 0, stream>>>(y2, y2, nullptr, nullptr);
    bimap_kernel<32, 16, 256><<<B, 256, 0, stream>>>(y2, W3, y3);
    eig_kernel<16, 8, 64, true><<<B, 64, 0, stream>>>(y3, out, fc_w, fc_b);
}

// Round 5
// 22314.888 us; speedup vs baseline: 1.0699x; 1.0699x over previous
//
#include <hip/hip_runtime.h>
#include <hip/hip_bf16.h>
#include <math.h>

#define EPS_REEIG 0.01f

// ---------------------------------------------------------------------------
// BiMap: Y[b] = W^T X[b] W.  One block per batch element. (unchanged, ~0.5ms)
// ---------------------------------------------------------------------------
template<int NIN, int NOUT, int BT>
__global__ void bimap_kernel(const float* __restrict__ X,
                             const float* __restrict__ W,
                             float* __restrict__ Y) {
    __shared__ float Ws[NIN * NOUT];
    __shared__ float T[NIN * NOUT];
    const int b = blockIdx.x;
    const float* Xb = X + (size_t)b * NIN * NIN;

    for (int e = threadIdx.x; e < NIN * NOUT; e += BT) Ws[e] = W[e];
    __syncthreads();

    for (int e = threadIdx.x; e < NIN * NOUT; e += BT) {
        const int i = e / NOUT;
        const int j = e % NOUT;
        float acc = 0.f;
        const float* xrow = Xb + (size_t)i * NIN;
#pragma unroll 8
        for (int k = 0; k < NIN; ++k) acc += xrow[k] * Ws[k * NOUT + j];
        T[e] = acc;
    }
    __syncthreads();

    for (int e = threadIdx.x; e < NOUT * NOUT; e += BT) {
        const int p = e / NOUT;
        const int q = e % NOUT;
        float acc = 0.f;
#pragma unroll 8
        for (int k = 0; k < NIN; ++k) acc += Ws[k * NOUT + p] * T[k * NOUT + q];
        Y[(size_t)b * NOUT * NOUT + e] = acc;
    }
}

// ---------------------------------------------------------------------------
// Wave-synchronous TWO-SIDED cyclic Jacobi. One wave (64 thr) per block,
// 64/N matrices per wave. A in LDS (col-major, pitch N+1); V in registers
// (lane jl owns eigenvector column jl, updated via shfl). Zero s_barrier:
// cross-lane LDS ordering = per-wave in-order DS execution + compiler fence.
//
// Numerics rationale (rounds 2-4 post-mortem): one-sided Hestenes floors at
// ~1e-3 symmetric-matrix error (V orthogonality error is linear in the Gram
// residual, amplified by the Gershgorin shift); the stage-3 log (slope
// 1/EPS=100) needs <3e-4. Two-sided keeps V orthogonal by construction
// (round 1 passed at absmax 0.0039). Sweep counts 10/9/8 are the proven set.
//   FINAL=false: writes R = V*max(lam,eps)*V^T (in-place safe)
//   FINAL=true : f=log(max(lam,eps)); out = vech(V f V^T) @ fc_w^T + fc_b
// ---------------------------------------------------------------------------
__device__ __forceinline__ void wave_fence() {
    // order all LDS ops of this wave across this point; block compiler motion
    asm volatile("s_waitcnt lgkmcnt(0)" ::: "memory");
    __builtin_amdgcn_sched_barrier(0);
}

template<int N, int SWEEPS, bool FINAL>
__global__ __launch_bounds__(64) void jacobi2s_kernel(
        const float* __restrict__ In, float* __restrict__ Out,
        const float* __restrict__ fc_w, const float* __restrict__ fc_b)
{
    constexpr int GP = 64 / N;      // matrices per wave
    constexpr int LD = N + 1;       // LDS pitch: stride 65/33/17 -> conflict-free

    __shared__ float Ls[GP][N][LD];
    __shared__ float Wt[FINAL ? 136 : 1][FINAL ? 8 : 1];
    __shared__ float Bs[FINAL ? 8 : 1];

    const int lane  = threadIdx.x & 63;
    const int jl    = lane & (N - 1);     // my column / row / eigvec index
    const int grp   = lane / N;           // matrix slot within wave
    const int gbase = lane & ~(N - 1);    // first lane of my group
    const int mb    = blockIdx.x * GP + grp;

    if constexpr (FINAL) {
        for (int t = threadIdx.x; t < 952; t += 64) {
            const int idx = t / 7, c = t % 7;
            Wt[idx][c] = fc_w[c * 136 + idx];
        }
        if (threadIdx.x < 7) Bs[threadIdx.x] = fc_b[threadIdx.x];
    }

    // ---- load A into LDS col-major: coalesced global reads ----
    {
        const float* inb = In + (size_t)mb * N * N;
        for (int t = 0; t < N; ++t) {
            // lanes jl=0..N-1 read consecutive addresses t*N+jl (coalesced);
            // element A[t][jl] -> Ls[grp][jl][t]; write stride LD: conflict-free
            Ls[grp][jl][t] = inb[t * N + jl];
        }
    }

    // ---- V = I in registers: lane jl holds eigenvector column jl ----
    float v[N];
#pragma unroll
    for (int i = 0; i < N; ++i) v[i] = (i == jl) ? 1.f : 0.f;

    if constexpr (FINAL) __syncthreads();   // Wt ready (one-time)
    wave_fence();                           // A staged

    // ---- two-sided cyclic Jacobi sweeps ----
    constexpr int m = N - 1;
    for (int sw = 0; sw < SWEEPS; ++sw) {
        for (int r = 0; r < m; ++r) {
            // round-robin partner of index jl in round r
            int pp;
            if (jl == m) {
                pp = r;
            } else {
                int o = jl - r; if (o < 0) o += m;
                if (o == 0) pp = m;
                else { pp = r + (m - o); if (pp >= m) pp -= m; }
            }
            const int lo = min(jl, pp);
            const int hi = jl ^ pp ^ lo;

            // rotation params: both lanes of the pair read identical values
            const float down = Ls[grp][jl][jl];
            const float dpar = Ls[grp][pp][pp];
            const float apq  = Ls[grp][hi][lo];   // A[lo][hi], shared copy
            float c = 1.f, s = 0.f;
            if (fabsf(apq) > 1e-36f) {
                const float dlo = (jl == lo) ? down : dpar;
                const float dhi = (jl == lo) ? dpar : down;
                const float tau = (dhi - dlo) / (2.f * apq);
                const float t = copysignf(1.f, tau) /
                                (fabsf(tau) + sqrtf(fmaf(tau, tau, 1.f)));
                c = rsqrtf(fmaf(t, t, 1.f));
                s = t * c;
            }
            const float se = (jl == lo) ? -s : s;  // col_lo' = c*lo - s*hi ; col_hi' = s*lo + c*hi

            // ---- column op: C = A*J (lane jl updates its column) ----
            {
                float* cown = &Ls[grp][jl][0];
                const float* cpar = &Ls[grp][pp][0];
#pragma unroll 4
                for (int i = 0; i < N; ++i) {
                    const float a = cown[i];
                    const float b = cpar[i];
                    cown[i] = fmaf(c, a, se * b);   // reads precede write (data dep)
                }
            }
            wave_fence();   // all columns written before row phase reads them

            // ---- row op: A' = J^T*C (lane jl updates its row) ----
            {
#pragma unroll 4
                for (int j = 0; j < N; ++j) {
                    const float a = Ls[grp][j][jl];
                    const float b = Ls[grp][j][pp];
                    Ls[grp][j][jl] = fmaf(c, a, se * b);
                }
            }

            // ---- V col op, in registers via shfl ----
            {
                const int psrc = gbase + pp;
#pragma unroll
                for (int i = 0; i < N; ++i) {
                    const float pv = __shfl(v[i], psrc, 64);
                    v[i] = fmaf(c, v[i], se * pv);
                }
            }
            wave_fence();   // rows committed before next round's param reads
        }
    }

    const float lam = Ls[grp][jl][jl];   // eigenvalue jl (diag of converged A)

    if constexpr (!FINAL) {
        // ---- ReEig: R = Vt Vt^T with Vt = V*sqrt(max(lam,eps)) ----
        const float sc = sqrtf(fmaxf(lam, EPS_REEIG));
        {
            float* cown = &Ls[grp][jl][0];   // overwrite A's column jl with Vt col jl
#pragma unroll
            for (int i = 0; i < N; ++i) cown[i] = v[i] * sc;
        }
        wave_fence();

        float acc[N];
#pragma unroll
        for (int i = 0; i < N; ++i) acc[i] = 0.f;
        for (int k = 0; k < N; ++k) {
            const float w = Ls[grp][k][jl];        // lane-varying: conflict-free
            const float* Lk = &Ls[grp][k][0];      // uniform: broadcast
#pragma unroll
            for (int i = 0; i < N; ++i) acc[i] = fmaf(Lk[i], w, acc[i]);
        }
        // write row jl of symmetric R (contiguous, float4)
        float4* orow = (float4*)(Out + (size_t)mb * N * N + (size_t)jl * N);
#pragma unroll
        for (int i4 = 0; i4 < N / 4; ++i4) {
            float4 o;
            o.x = acc[4*i4+0]; o.y = acc[4*i4+1];
            o.z = acc[4*i4+2]; o.w = acc[4*i4+3];
            orow[i4] = o;
        }
    } else {
        // ---- LogEig + vech + FC (N=16): lane jl owns eigvec jl, weight f ----
        const float f = logf(fmaxf(lam, EPS_REEIG));

        float q[7];
#pragma unroll
        for (int c = 0; c < 7; ++c) q[c] = 0.f;
#pragma unroll
        for (int i = 0; i < N; ++i) {
#pragma unroll
            for (int j = i; j < N; ++j) {
                const int idx = 16 * i - (i * (i + 1)) / 2 + j;  // vech (triu row-major)
                const float o = v[i] * v[j];
#pragma unroll
                for (int c = 0; c < 7; ++c) q[c] = fmaf(o, Wt[idx][c], q[c]);
            }
        }
#pragma unroll
        for (int c = 0; c < 7; ++c) q[c] *= f;
        // sum the 16 rank-1 contributions across the group's lanes
#pragma unroll
        for (int st = 1; st < N; st <<= 1) {
#pragma unroll
            for (int c = 0; c < 7; ++c) q[c] += __shfl_xor(q[c], st, 64);
        }
#pragma unroll
        for (int c = 0; c < 7; ++c)
            if (jl == c) Out[(size_t)mb * 7 + c] = q[c] + Bs[c];
    }
}

// ---------------------------------------------------------------------------
extern "C" void kernel_launch(void* const* d_in, const int* in_sizes, int n_in,
                              void* d_out, int out_size, void* d_ws, size_t ws_size,
                              hipStream_t stream) {
    const float* x    = (const float*)d_in[0];   // [B,128,128]
    const float* W1   = (const float*)d_in[1];   // [128,64]
    const float* W2   = (const float*)d_in[2];   // [64,32]
    const float* W3   = (const float*)d_in[3];   // [32,16]
    const float* fc_w = (const float*)d_in[4];   // [7,136]
    const float* fc_b = (const float*)d_in[5];   // [7]
    float* out = (float*)d_out;                  // [B,7]

    const int B = in_sizes[0] / (128 * 128);

    float* y1 = (float*)d_ws;                    // [B,64,64]
    float* y2 = y1 + (size_t)B * 64 * 64;        // [B,32,32]
    float* y3 = y2 + (size_t)B * 32 * 32;        // [B,16,16]

    bimap_kernel<128, 64, 256><<<B, 256, 0, stream>>>(x, W1, y1);
    jacobi2s_kernel<64, 10, false><<<B, 64, 0, stream>>>(y1, y1, nullptr, nullptr);
    bimap_kernel<64, 32, 256><<<B, 256, 0, stream>>>(y1, W2, y2);
    jacobi2s_kernel<32, 9, false><<<B / 2, 64, 0, stream>>>(y2, y2, nullptr, nullptr);
    bimap_kernel<32, 16, 256><<<B, 256, 0, stream>>>(y2, W3, y3);
    jacobi2s_kernel<16, 8, true><<<B / 4, 64, 0, stream>>>(y3, out, fc_w, fc_b);
}

// Round 6
// 13182.605 us; speedup vs baseline: 1.8111x; 1.6928x over previous
//
#include <hip/hip_runtime.h>
#include <hip/hip_bf16.h>
#include <math.h>

#define EPS_REEIG 0.01f

// ---------------------------------------------------------------------------
// BiMap: Y[b] = W^T X[b] W.  One block per batch element. float4 X loads.
// ---------------------------------------------------------------------------
template<int NIN, int NOUT, int BT>
__global__ void bimap_kernel(const float* __restrict__ X,
                             const float* __restrict__ W,
                             float* __restrict__ Y) {
    __shared__ float Ws[NIN * NOUT];
    __shared__ float T[NIN * NOUT];
    const int b = blockIdx.x;
    const float* Xb = X + (size_t)b * NIN * NIN;

    for (int e = threadIdx.x; e < NIN * NOUT; e += BT) Ws[e] = W[e];
    __syncthreads();

    for (int e = threadIdx.x; e < NIN * NOUT; e += BT) {
        const int i = e / NOUT;
        const int j = e % NOUT;
        float acc = 0.f;
        const float4* xrow = (const float4*)(Xb + (size_t)i * NIN);
#pragma unroll 4
        for (int k4 = 0; k4 < NIN / 4; ++k4) {
            const float4 xv = xrow[k4];
            acc = fmaf(xv.x, Ws[(4 * k4 + 0) * NOUT + j], acc);
            acc = fmaf(xv.y, Ws[(4 * k4 + 1) * NOUT + j], acc);
            acc = fmaf(xv.z, Ws[(4 * k4 + 2) * NOUT + j], acc);
            acc = fmaf(xv.w, Ws[(4 * k4 + 3) * NOUT + j], acc);
        }
        T[e] = acc;
    }
    __syncthreads();

    for (int e = threadIdx.x; e < NOUT * NOUT; e += BT) {
        const int p = e / NOUT;
        const int q = e % NOUT;
        float acc = 0.f;
#pragma unroll 8
        for (int k = 0; k < NIN; ++k) acc += Ws[k * NOUT + p] * T[k * NOUT + q];
        Y[(size_t)b * NOUT * NOUT + e] = acc;
    }
}

// ---------------------------------------------------------------------------
// Wave-synchronous TWO-SIDED cyclic Jacobi, v2 (b128 data plumbing).
// Same algebra/sweeps as the passing round-5 kernel; data movement redone:
//  - own column mirrored in registers (no re-read)
//  - pitch-N storage with 16B XOR swizzle -> conflict-free ds_*_b128
//  - transpose trick: col phase writes C row-major (b32 scatter); row phase
//    reads rows contiguously (b128); A' row jl == A' col jl (symmetry) is
//    written back col-major (b128), restoring the invariant.
// LDS ordering within the single wave is enforced by lgkmcnt(0) fences.
//   FINAL=false: writes R = V*max(lam,eps)*V^T
//   FINAL=true : f=log(max(lam,eps)); out = vech(V f V^T) @ fc_w^T + fc_b
// ---------------------------------------------------------------------------
__device__ __forceinline__ void wave_fence() {
    asm volatile("s_waitcnt lgkmcnt(0)" ::: "memory");
    __builtin_amdgcn_sched_barrier(0);
}

template<int N, int SWEEPS, bool FINAL>
__global__ __launch_bounds__(64) void jacobi2s_v2(
        const float* __restrict__ In, float* __restrict__ Out,
        const float* __restrict__ fc_w, const float* __restrict__ fc_b)
{
    constexpr int GP    = 64 / N;       // matrices per wave
    constexpr int BMASK = N / 4 - 1;    // 16B-block swizzle mask

    __shared__ float Ab[GP][N * N];
    __shared__ float Wt[FINAL ? 136 : 1][FINAL ? 8 : 1];
    __shared__ float Bs[FINAL ? 8 : 1];

    const int lane  = threadIdx.x & 63;
    const int jl    = lane & (N - 1);     // my column / row / eigvec index
    const int grp   = lane / N;           // matrix slot within wave
    const int gbase = lane & ~(N - 1);    // first lane of my group
    const int mb    = blockIdx.x * GP + grp;

    float* Am = &Ab[grp][0];

    if constexpr (FINAL) {
        for (int t = threadIdx.x; t < 952; t += 64)
            Wt[t / 7][t % 7] = fc_w[(t % 7) * 136 + t / 7];
        if (threadIdx.x < 7) Bs[threadIdx.x] = fc_b[threadIdx.x];
    }

    // ---- load row jl (== col jl by symmetry) from global, coalesced ----
    float a[N], v[N];
    {
        const float4* row = (const float4*)(In + (size_t)mb * N * N + (size_t)jl * N);
#pragma unroll
        for (int k = 0; k < N / 4; ++k) {
            const float4 q = row[k];
            a[4*k+0] = q.x; a[4*k+1] = q.y; a[4*k+2] = q.z; a[4*k+3] = q.w;
        }
    }
#pragma unroll
    for (int i = 0; i < N; ++i) v[i] = (i == jl) ? 1.f : 0.f;

    // ---- store col-major swizzled (b128) ----
#pragma unroll
    for (int k = 0; k < N / 4; ++k) {
        float4 q; q.x = a[4*k]; q.y = a[4*k+1]; q.z = a[4*k+2]; q.w = a[4*k+3];
        *(float4*)&Am[jl * N + ((k ^ (jl & BMASK)) << 2)] = q;
    }
    if constexpr (FINAL) __syncthreads();   // Wt ready (one-time)
    wave_fence();

    // ---- two-sided cyclic Jacobi sweeps ----
    constexpr int m = N - 1;
    for (int sw = 0; sw < SWEEPS; ++sw) {
        for (int r = 0; r < m; ++r) {
            int pp;
            if (jl == m) pp = r;
            else {
                int o = jl - r; if (o < 0) o += m;
                if (o == 0) pp = m;
                else { pp = r + (m - o); if (pp >= m) pp -= m; }
            }
            const int lo = min(jl, pp);
            const int hi = jl ^ pp ^ lo;

            // rotation params (swizzled b32 reads; pair reads identical values)
            const float down = Am[jl * N + (((jl >> 2) ^ (jl & BMASK)) << 2) + (jl & 3)];
            const float dpar = Am[pp * N + (((pp >> 2) ^ (pp & BMASK)) << 2) + (pp & 3)];
            const float apq  = Am[hi * N + (((lo >> 2) ^ (hi & BMASK)) << 2) + (lo & 3)];
            float c = 1.f, s = 0.f;
            if (fabsf(apq) > 1e-36f) {
                const float dlo = (jl == lo) ? down : dpar;
                const float dhi = (jl == lo) ? dpar : down;
                const float tau = (dhi - dlo) / (2.f * apq);
                const float t = copysignf(1.f, tau) /
                                (fabsf(tau) + sqrtf(fmaf(tau, tau, 1.f)));
                c = rsqrtf(fmaf(t, t, 1.f));
                s = t * c;
            }
            const float se = (jl == lo) ? -s : s;

            // ---- col phase: C col jl = c*own + se*partner  (partner via b128)
            float pc[N];
#pragma unroll
            for (int k = 0; k < N / 4; ++k) {
                const float4 q = *(const float4*)&Am[pp * N + ((k ^ (pp & BMASK)) << 2)];
                pc[4*k+0] = q.x; pc[4*k+1] = q.y; pc[4*k+2] = q.z; pc[4*k+3] = q.w;
            }
#pragma unroll
            for (int i = 0; i < N; ++i) pc[i] = fmaf(c, a[i], se * pc[i]);
            wave_fence();                      // all cols checked out
            // ---- transpose write: C[i][jl] -> row-slot i, elem jl (b32 scatter)
#pragma unroll
            for (int i = 0; i < N; ++i)
                Am[i * N + (((jl >> 2) ^ (i & BMASK)) << 2) + (jl & 3)] = pc[i];
            wave_fence();

            // ---- row phase: rows contiguous now (b128) ----
#pragma unroll
            for (int k = 0; k < N / 4; ++k) {
                const float4 q = *(const float4*)&Am[jl * N + ((k ^ (jl & BMASK)) << 2)];
                a[4*k+0] = q.x; a[4*k+1] = q.y; a[4*k+2] = q.z; a[4*k+3] = q.w;
            }
            float pr[N];
#pragma unroll
            for (int k = 0; k < N / 4; ++k) {
                const float4 q = *(const float4*)&Am[pp * N + ((k ^ (pp & BMASK)) << 2)];
                pr[4*k+0] = q.x; pr[4*k+1] = q.y; pr[4*k+2] = q.z; pr[4*k+3] = q.w;
            }
#pragma unroll
            for (int i = 0; i < N; ++i) a[i] = fmaf(c, a[i], se * pr[i]);
            wave_fence();                      // rows all checked out
            // ---- A' row jl == A' col jl: restore col-major invariant (b128)
#pragma unroll
            for (int k = 0; k < N / 4; ++k) {
                float4 q; q.x = a[4*k]; q.y = a[4*k+1]; q.z = a[4*k+2]; q.w = a[4*k+3];
                *(float4*)&Am[jl * N + ((k ^ (jl & BMASK)) << 2)] = q;
            }
            // ---- V col mix in registers via shfl ----
            {
                const int psrc = gbase + pp;
#pragma unroll
                for (int i = 0; i < N; ++i) {
                    const float pv = __shfl(v[i], psrc, 64);
                    v[i] = fmaf(c, v[i], se * pv);
                }
            }
            wave_fence();                      // col-major restored for next round
        }
    }

    const float lam = Am[jl * N + (((jl >> 2) ^ (jl & BMASK)) << 2) + (jl & 3)];

    if constexpr (!FINAL) {
        // ---- ReEig: R = Vt Vt^T with Vt = V*sqrt(max(lam,eps)) ----
        const float sc = sqrtf(fmaxf(lam, EPS_REEIG));
#pragma unroll
        for (int k = 0; k < N / 4; ++k) {
            float4 q;
            q.x = v[4*k+0]*sc; q.y = v[4*k+1]*sc; q.z = v[4*k+2]*sc; q.w = v[4*k+3]*sc;
            *(float4*)&Am[jl * N + ((k ^ (jl & BMASK)) << 2)] = q;
        }
        wave_fence();

        float acc[N];
#pragma unroll
        for (int i = 0; i < N; ++i) acc[i] = 0.f;
        for (int k = 0; k < N; ++k) {
            const float w = Am[k * N + (((jl >> 2) ^ (k & BMASK)) << 2) + (jl & 3)];
#pragma unroll
            for (int t = 0; t < N / 4; ++t) {
                const float4 lk = *(const float4*)&Am[k * N + ((t ^ (k & BMASK)) << 2)];
                acc[4*t+0] = fmaf(lk.x, w, acc[4*t+0]);
                acc[4*t+1] = fmaf(lk.y, w, acc[4*t+1]);
                acc[4*t+2] = fmaf(lk.z, w, acc[4*t+2]);
                acc[4*t+3] = fmaf(lk.w, w, acc[4*t+3]);
            }
        }
        float4* orow = (float4*)(Out + (size_t)mb * N * N + (size_t)jl * N);
#pragma unroll
        for (int k = 0; k < N / 4; ++k) {
            float4 q; q.x = acc[4*k]; q.y = acc[4*k+1]; q.z = acc[4*k+2]; q.w = acc[4*k+3];
            orow[k] = q;
        }
    } else {
        // ---- LogEig + vech + FC (N=16): lane jl owns eigvec jl, weight f ----
        const float f = logf(fmaxf(lam, EPS_REEIG));

        float q[7];
#pragma unroll
        for (int c = 0; c < 7; ++c) q[c] = 0.f;
#pragma unroll
        for (int i = 0; i < N; ++i) {
#pragma unroll
            for (int j = i; j < N; ++j) {
                const int idx = 16 * i - (i * (i + 1)) / 2 + j;  // vech (triu row-major)
                const float o = v[i] * v[j];
#pragma unroll
                for (int c = 0; c < 7; ++c) q[c] = fmaf(o, Wt[idx][c], q[c]);
            }
        }
#pragma unroll
        for (int c = 0; c < 7; ++c) q[c] *= f;
#pragma unroll
        for (int st = 1; st < N; st <<= 1) {
#pragma unroll
            for (int c = 0; c < 7; ++c) q[c] += __shfl_xor(q[c], st, 64);
        }
#pragma unroll
        for (int c = 0; c < 7; ++c)
            if (jl == c) Out[(size_t)mb * 7 + c] = q[c] + Bs[c];
    }
}

// ---------------------------------------------------------------------------
extern "C" void kernel_launch(void* const* d_in, const int* in_sizes, int n_in,
                              void* d_out, int out_size, void* d_ws, size_t ws_size,
                              hipStream_t stream) {
    const float* x    = (const float*)d_in[0];   // [B,128,128]
    const float* W1   = (const float*)d_in[1];   // [128,64]
    const float* W2   = (const float*)d_in[2];   // [64,32]
    const float* W3   = (const float*)d_in[3];   // [32,16]
    const float* fc_w = (const float*)d_in[4];   // [7,136]
    const float* fc_b = (const float*)d_in[5];   // [7]
    float* out = (float*)d_out;                  // [B,7]

    const int B = in_sizes[0] / (128 * 128);

    float* y1 = (float*)d_ws;                    // [B,64,64]
    float* y2 = y1 + (size_t)B * 64 * 64;        // [B,32,32]
    float* y3 = y2 + (size_t)B * 32 * 32;        // [B,16,16]

    bimap_kernel<128, 64, 256><<<B, 256, 0, stream>>>(x, W1, y1);
    jacobi2s_v2<64, 10, false><<<B, 64, 0, stream>>>(y1, y1, nullptr, nullptr);
    bimap_kernel<64, 32, 256><<<B, 256, 0, stream>>>(y1, W2, y2);
    jacobi2s_v2<32, 9, false><<<B / 2, 64, 0, stream>>>(y2, y2, nullptr, nullptr);
    bimap_kernel<32, 16, 256><<<B, 256, 0, stream>>>(y2, W3, y3);
    jacobi2s_v2<16, 8, true><<<B / 4, 64, 0, stream>>>(y3, out, fc_w, fc_b);
}

// Round 7
// 9920.165 us; speedup vs baseline: 2.4067x; 1.3289x over previous
//
#include <hip/hip_runtime.h>
#include <hip/hip_bf16.h>
#include <math.h>

#define EPS_REEIG 0.01f

// ---------------------------------------------------------------------------
// BiMap: Y[b] = W^T X[b] W.  One block per batch element. float4 X loads.
// ---------------------------------------------------------------------------
template<int NIN, int NOUT, int BT>
__global__ void bimap_kernel(const float* __restrict__ X,
                             const float* __restrict__ W,
                             float* __restrict__ Y) {
    __shared__ float Ws[NIN * NOUT];
    __shared__ float T[NIN * NOUT];
    const int b = blockIdx.x;
    const float* Xb = X + (size_t)b * NIN * NIN;

    for (int e = threadIdx.x; e < NIN * NOUT; e += BT) Ws[e] = W[e];
    __syncthreads();

    for (int e = threadIdx.x; e < NIN * NOUT; e += BT) {
        const int i = e / NOUT;
        const int j = e % NOUT;
        float acc = 0.f;
        const float4* xrow = (const float4*)(Xb + (size_t)i * NIN);
#pragma unroll 4
        for (int k4 = 0; k4 < NIN / 4; ++k4) {
            const float4 xv = xrow[k4];
            acc = fmaf(xv.x, Ws[(4 * k4 + 0) * NOUT + j], acc);
            acc = fmaf(xv.y, Ws[(4 * k4 + 1) * NOUT + j], acc);
            acc = fmaf(xv.z, Ws[(4 * k4 + 2) * NOUT + j], acc);
            acc = fmaf(xv.w, Ws[(4 * k4 + 3) * NOUT + j], acc);
        }
        T[e] = acc;
    }
    __syncthreads();

    for (int e = threadIdx.x; e < NOUT * NOUT; e += BT) {
        const int p = e / NOUT;
        const int q = e % NOUT;
        float acc = 0.f;
#pragma unroll 8
        for (int k = 0; k < NIN; ++k) acc += Ws[k * NOUT + p] * T[k * NOUT + q];
        Y[(size_t)b * NOUT * NOUT + e] = acc;
    }
}

// ---------------------------------------------------------------------------
// Wave-synchronous TWO-SIDED cyclic Jacobi, v3 = v2 + sweep-level early exit.
//  - own column mirrored in registers; pitch-N + 16B XOR swizzle -> b128
//  - transpose trick for the row phase (see R6)
//  - NEW: after each sweep, exit when total off-diag Frobenius^2 < 1e-8.
//    Off^2 is computed by masking the diagonal with a static-unrolled
//    (i==jl) select -- NOT as tot - d^2, whose fp32 cancellation noise
//    (~3e-5 at ||col||^2~256) would swamp the 1e-8 threshold and never fire.
//    Quadratic convergence => typical exit at sweep ~7 of cap 10.
//    Deterministic: same input -> same trajectory -> same exit sweep.
//   FINAL=false: writes R = V*max(lam,eps)*V^T
//   FINAL=true : f=log(max(lam,eps)); out = vech(V f V^T) @ fc_w^T + fc_b
// ---------------------------------------------------------------------------
__device__ __forceinline__ void wave_fence() {
    asm volatile("s_waitcnt lgkmcnt(0)" ::: "memory");
    __builtin_amdgcn_sched_barrier(0);
}

template<int N, int SWEEPS, bool FINAL>
__global__ __launch_bounds__(64) void jacobi2s_v3(
        const float* __restrict__ In, float* __restrict__ Out,
        const float* __restrict__ fc_w, const float* __restrict__ fc_b)
{
    constexpr int GP    = 64 / N;       // matrices per wave
    constexpr int BMASK = N / 4 - 1;    // 16B-block swizzle mask

    __shared__ float Ab[GP][N * N];
    __shared__ float Wt[FINAL ? 136 : 1][FINAL ? 8 : 1];
    __shared__ float Bs[FINAL ? 8 : 1];

    const int lane  = threadIdx.x & 63;
    const int jl    = lane & (N - 1);     // my column / row / eigvec index
    const int grp   = lane / N;           // matrix slot within wave
    const int gbase = lane & ~(N - 1);    // first lane of my group
    const int mb    = blockIdx.x * GP + grp;

    float* Am = &Ab[grp][0];

    if constexpr (FINAL) {
        for (int t = threadIdx.x; t < 952; t += 64)
            Wt[t / 7][t % 7] = fc_w[(t % 7) * 136 + t / 7];
        if (threadIdx.x < 7) Bs[threadIdx.x] = fc_b[threadIdx.x];
    }

    // ---- load row jl (== col jl by symmetry) from global, coalesced ----
    float a[N], v[N];
    {
        const float4* row = (const float4*)(In + (size_t)mb * N * N + (size_t)jl * N);
#pragma unroll
        for (int k = 0; k < N / 4; ++k) {
            const float4 q = row[k];
            a[4*k+0] = q.x; a[4*k+1] = q.y; a[4*k+2] = q.z; a[4*k+3] = q.w;
        }
    }
#pragma unroll
    for (int i = 0; i < N; ++i) v[i] = (i == jl) ? 1.f : 0.f;

    // ---- store col-major swizzled (b128) ----
#pragma unroll
    for (int k = 0; k < N / 4; ++k) {
        float4 q; q.x = a[4*k]; q.y = a[4*k+1]; q.z = a[4*k+2]; q.w = a[4*k+3];
        *(float4*)&Am[jl * N + ((k ^ (jl & BMASK)) << 2)] = q;
    }
    if constexpr (FINAL) __syncthreads();   // Wt ready (one-time)
    wave_fence();

    // ---- two-sided cyclic Jacobi sweeps ----
    constexpr int m = N - 1;
    for (int sw = 0; sw < SWEEPS; ++sw) {
        for (int r = 0; r < m; ++r) {
            int pp;
            if (jl == m) pp = r;
            else {
                int o = jl - r; if (o < 0) o += m;
                if (o == 0) pp = m;
                else { pp = r + (m - o); if (pp >= m) pp -= m; }
            }
            const int lo = min(jl, pp);
            const int hi = jl ^ pp ^ lo;

            // rotation params (swizzled b32 reads; pair reads identical values)
            const float down = Am[jl * N + (((jl >> 2) ^ (jl & BMASK)) << 2) + (jl & 3)];
            const float dpar = Am[pp * N + (((pp >> 2) ^ (pp & BMASK)) << 2) + (pp & 3)];
            const float apq  = Am[hi * N + (((lo >> 2) ^ (hi & BMASK)) << 2) + (lo & 3)];
            float c = 1.f, s = 0.f;
            if (fabsf(apq) > 1e-36f) {
                const float dlo = (jl == lo) ? down : dpar;
                const float dhi = (jl == lo) ? dpar : down;
                const float tau = (dhi - dlo) / (2.f * apq);
                const float t = copysignf(1.f, tau) /
                                (fabsf(tau) + sqrtf(fmaf(tau, tau, 1.f)));
                c = rsqrtf(fmaf(t, t, 1.f));
                s = t * c;
            }
            const float se = (jl == lo) ? -s : s;

            // ---- col phase: C col jl = c*own + se*partner  (partner via b128)
            float pc[N];
#pragma unroll
            for (int k = 0; k < N / 4; ++k) {
                const float4 q = *(const float4*)&Am[pp * N + ((k ^ (pp & BMASK)) << 2)];
                pc[4*k+0] = q.x; pc[4*k+1] = q.y; pc[4*k+2] = q.z; pc[4*k+3] = q.w;
            }
#pragma unroll
            for (int i = 0; i < N; ++i) pc[i] = fmaf(c, a[i], se * pc[i]);
            wave_fence();                      // all cols checked out
            // ---- transpose write: C[i][jl] -> row-slot i, elem jl (b32 scatter)
#pragma unroll
            for (int i = 0; i < N; ++i)
                Am[i * N + (((jl >> 2) ^ (i & BMASK)) << 2) + (jl & 3)] = pc[i];
            wave_fence();

            // ---- row phase: rows contiguous now (b128) ----
#pragma unroll
            for (int k = 0; k < N / 4; ++k) {
                const float4 q = *(const float4*)&Am[jl * N + ((k ^ (jl & BMASK)) << 2)];
                a[4*k+0] = q.x; a[4*k+1] = q.y; a[4*k+2] = q.z; a[4*k+3] = q.w;
            }
            float pr[N];
#pragma unroll
            for (int k = 0; k < N / 4; ++k) {
                const float4 q = *(const float4*)&Am[pp * N + ((k ^ (pp & BMASK)) << 2)];
                pr[4*k+0] = q.x; pr[4*k+1] = q.y; pr[4*k+2] = q.z; pr[4*k+3] = q.w;
            }
#pragma unroll
            for (int i = 0; i < N; ++i) a[i] = fmaf(c, a[i], se * pr[i]);
            wave_fence();                      // rows all checked out
            // ---- A' row jl == A' col jl: restore col-major invariant (b128)
#pragma unroll
            for (int k = 0; k < N / 4; ++k) {
                float4 q; q.x = a[4*k]; q.y = a[4*k+1]; q.z = a[4*k+2]; q.w = a[4*k+3];
                *(float4*)&Am[jl * N + ((k ^ (jl & BMASK)) << 2)] = q;
            }
            // ---- V col mix in registers via shfl ----
            {
                const int psrc = gbase + pp;
#pragma unroll
                for (int i = 0; i < N; ++i) {
                    const float pv = __shfl(v[i], psrc, 64);
                    v[i] = fmaf(c, v[i], se * pv);
                }
            }
            wave_fence();                      // col-major restored for next round
        }

        // ---- sweep-level convergence check: total off-diag Frobenius^2 ----
        // Diagonal masked by static-unrolled select (no tot-d^2 cancellation).
        {
            float off2 = 0.f;
#pragma unroll
            for (int i = 0; i < N; ++i) {
                const float e = (i == jl) ? 0.f : a[i];
                off2 = fmaf(e, e, off2);
            }
#pragma unroll
            for (int st = 1; st < N; st <<= 1) off2 += __shfl_xor(off2, st, 64);
            if (__all(off2 < 1e-8f)) break;    // wave-uniform exit (all groups)
        }
    }

    const float lam = Am[jl * N + (((jl >> 2) ^ (jl & BMASK)) << 2) + (jl & 3)];

    if constexpr (!FINAL) {
        // ---- ReEig: R = Vt Vt^T with Vt = V*sqrt(max(lam,eps)) ----
        const float sc = sqrtf(fmaxf(lam, EPS_REEIG));
#pragma unroll
        for (int k = 0; k < N / 4; ++k) {
            float4 q;
            q.x = v[4*k+0]*sc; q.y = v[4*k+1]*sc; q.z = v[4*k+2]*sc; q.w = v[4*k+3]*sc;
            *(float4*)&Am[jl * N + ((k ^ (jl & BMASK)) << 2)] = q;
        }
        wave_fence();

        float acc[N];
#pragma unroll
        for (int i = 0; i < N; ++i) acc[i] = 0.f;
        for (int k = 0; k < N; ++k) {
            const float w = Am[k * N + (((jl >> 2) ^ (k & BMASK)) << 2) + (jl & 3)];
#pragma unroll
            for (int t = 0; t < N / 4; ++t) {
                const float4 lk = *(const float4*)&Am[k * N + ((t ^ (k & BMASK)) << 2)];
                acc[4*t+0] = fmaf(lk.x, w, acc[4*t+0]);
                acc[4*t+1] = fmaf(lk.y, w, acc[4*t+1]);
                acc[4*t+2] = fmaf(lk.z, w, acc[4*t+2]);
                acc[4*t+3] = fmaf(lk.w, w, acc[4*t+3]);
            }
        }
        float4* orow = (float4*)(Out + (size_t)mb * N * N + (size_t)jl * N);
#pragma unroll
        for (int k = 0; k < N / 4; ++k) {
            float4 q; q.x = acc[4*k]; q.y = acc[4*k+1]; q.z = acc[4*k+2]; q.w = acc[4*k+3];
            orow[k] = q;
        }
    } else {
        // ---- LogEig + vech + FC (N=16): lane jl owns eigvec jl, weight f ----
        const float f = logf(fmaxf(lam, EPS_REEIG));

        float q[7];
#pragma unroll
        for (int c = 0; c < 7; ++c) q[c] = 0.f;
#pragma unroll
        for (int i = 0; i < N; ++i) {
#pragma unroll
            for (int j = i; j < N; ++j) {
                const int idx = 16 * i - (i * (i + 1)) / 2 + j;  // vech (triu row-major)
                const float o = v[i] * v[j];
#pragma unroll
                for (int c = 0; c < 7; ++c) q[c] = fmaf(o, Wt[idx][c], q[c]);
            }
        }
#pragma unroll
        for (int c = 0; c < 7; ++c) q[c] *= f;
#pragma unroll
        for (int st = 1; st < N; st <<= 1) {
#pragma unroll
            for (int c = 0; c < 7; ++c) q[c] += __shfl_xor(q[c], st, 64);
        }
#pragma unroll
        for (int c = 0; c < 7; ++c)
            if (jl == c) Out[(size_t)mb * 7 + c] = q[c] + Bs[c];
    }
}

// ---------------------------------------------------------------------------
extern "C" void kernel_launch(void* const* d_in, const int* in_sizes, int n_in,
                              void* d_out, int out_size, void* d_ws, size_t ws_size,
                              hipStream_t stream) {
    const float* x    = (const float*)d_in[0];   // [B,128,128]
    const float* W1   = (const float*)d_in[1];   // [128,64]
    const float* W2   = (const float*)d_in[2];   // [64,32]
    const float* W3   = (const float*)d_in[3];   // [32,16]
    const float* fc_w = (const float*)d_in[4];   // [7,136]
    const float* fc_b = (const float*)d_in[5];   // [7]
    float* out = (float*)d_out;                  // [B,7]

    const int B = in_sizes[0] / (128 * 128);

    float* y1 = (float*)d_ws;                    // [B,64,64]
    float* y2 = y1 + (size_t)B * 64 * 64;        // [B,32,32]
    float* y3 = y2 + (size_t)B * 32 * 32;        // [B,16,16]

    bimap_kernel<128, 64, 256><<<B, 256, 0, stream>>>(x, W1, y1);
    jacobi2s_v3<64, 10, false><<<B, 64, 0, stream>>>(y1, y1, nullptr, nullptr);
    bimap_kernel<64, 32, 256><<<B, 256, 0, stream>>>(y1, W2, y2);
    jacobi2s_v3<32, 9, false><<<B / 2, 64, 0, stream>>>(y2, y2, nullptr, nullptr);
    bimap_kernel<32, 16, 256><<<B, 256, 0, stream>>>(y2, W3, y3);
    jacobi2s_v3<16, 8, true><<<B / 4, 64, 0, stream>>>(y3, out, fc_w, fc_b);
}